// Round 5
// baseline (562.139 us; speedup 1.0000x reference)
//
#include <hip/hip_runtime.h>

#define SEQ 4096
#define HID 512
#define NB  4
#define N3  1536

typedef _Float16 half_t;
typedef __attribute__((ext_vector_type(8))) _Float16 half8;
typedef __attribute__((ext_vector_type(4))) float f32x4;

#define GLOAD_LDS16(gp, lp) __builtin_amdgcn_global_load_lds((gp), (lp), 16, 0, 0)

// ---------------- convert x (f32) -> f16 ----------------
__global__ void k_cvt(const float* __restrict__ x, half_t* __restrict__ xh, int n4) {
  int i = blockIdx.x * blockDim.x + threadIdx.x;
  int stride = gridDim.x * blockDim.x;
  for (; i < n4; i += stride) {
    float4 v = reinterpret_cast<const float4*>(x)[i];
    union { half_t h[4]; short4 s; } u;
    u.h[0] = (half_t)v.x; u.h[1] = (half_t)v.y;
    u.h[2] = (half_t)v.z; u.h[3] = (half_t)v.w;
    reinterpret_cast<short4*>(xh)[i] = u.s;
  }
}

// ---------------- W [512][1536] f32 -> Wt [1536][512] f16 ----------------
__global__ void k_tw(const float* __restrict__ W, half_t* __restrict__ Wt) {
  __shared__ half_t tile[64][65];
  const int n0 = blockIdx.x * 64;
  const int k0 = blockIdx.y * 64;
  const int tx = threadIdx.x & 63, ty = threadIdx.x >> 6;
#pragma unroll
  for (int i = 0; i < 64; i += 4)
    tile[ty + i][tx] = (half_t)W[(size_t)(k0 + ty + i) * N3 + n0 + tx];
  __syncthreads();
#pragma unroll
  for (int i = 0; i < 64; i += 4)
    Wt[(size_t)(n0 + ty + i) * HID + k0 + tx] = tile[tx][ty + i];
}

// ---------------- QKV projection GEMM ----------------
__launch_bounds__(256)
__global__ void k_qkv(const half_t* __restrict__ xh, const half_t* __restrict__ Wt,
                      const float* __restrict__ bias,
                      half_t* __restrict__ Qh, half_t* __restrict__ Kh,
                      half_t* __restrict__ Vt) {
  __shared__ half_t sA[128 * 32];
  __shared__ half_t sB[128 * 32];
  const int t = threadIdx.x;
  const int m0 = blockIdx.y * 128;
  const int n0 = blockIdx.x * 128;
  const int lane = t & 63, wid = t >> 6;
  const int wr = (wid >> 1) * 64, wc = (wid & 1) * 64;
  const int lrow = lane & 15, lks = lane >> 4;
  const int s1 = t, s2 = t + 256;
  const int ar1 = s1 >> 2, ac1 = (s1 & 3) * 8;
  const int ar2 = s2 >> 2, ac2 = (s2 & 3) * 8;

  f32x4 acc[4][4] = {};

  for (int k0 = 0; k0 < HID; k0 += 32) {
    __syncthreads();
    GLOAD_LDS16(xh + (size_t)(m0 + ar1) * HID + k0 + ac1, &sA[s1 * 8]);
    GLOAD_LDS16(xh + (size_t)(m0 + ar2) * HID + k0 + ac2, &sA[s2 * 8]);
    GLOAD_LDS16(Wt + (size_t)(n0 + ar1) * HID + k0 + ac1, &sB[s1 * 8]);
    GLOAD_LDS16(Wt + (size_t)(n0 + ar2) * HID + k0 + ac2, &sB[s2 * 8]);
    __syncthreads();
    half8 a[4], b[4];
#pragma unroll
    for (int m = 0; m < 4; ++m)
      a[m] = *reinterpret_cast<const half8*>(&sA[(wr + m * 16 + lrow) * 32 + lks * 8]);
#pragma unroll
    for (int n = 0; n < 4; ++n)
      b[n] = *reinterpret_cast<const half8*>(&sB[(wc + n * 16 + lrow) * 32 + lks * 8]);
#pragma unroll
    for (int m = 0; m < 4; ++m)
#pragma unroll
      for (int n = 0; n < 4; ++n)
        acc[m][n] = __builtin_amdgcn_mfma_f32_16x16x32_f16(a[m], b[n], acc[m][n], 0, 0, 0);
  }

  const float scale = 0.04419417382415922f;  // 1/sqrt(512)
  const int region = n0 >> 9;  // 0=Q, 1=K, 2=V (uniform per block)
#pragma unroll
  for (int m = 0; m < 4; ++m) {
#pragma unroll
    for (int n = 0; n < 4; ++n) {
      const int col = n0 + wc + n * 16 + lrow;
#pragma unroll
      for (int r = 0; r < 4; ++r) {
        const int row = m0 + wr + m * 16 + lks * 4 + r;
        float v = acc[m][n][r] + bias[col];
        if (region == 0) {
          Qh[(size_t)row * HID + col] = (half_t)(v * scale);
        } else if (region == 1) {
          Kh[(size_t)row * HID + (col - 512)] = (half_t)v;
        } else {
          const int bb = row >> 12, ml = row & (SEQ - 1);
          Vt[((size_t)bb * HID + (col - 1024)) * SEQ + ml] = (half_t)v;
        }
      }
    }
  }
}

// ---------------- scores = Q @ K^T, plus per-tile softmax partials ----------------
__launch_bounds__(256)
__global__ void k_qk(const half_t* __restrict__ Qh, const half_t* __restrict__ Kh,
                     float* __restrict__ S, float2* __restrict__ part) {
  __shared__ half_t sA[128 * 32];
  __shared__ half_t sB[128 * 32];
  __shared__ float lm[2][128], ls[2][128];
  const int t = threadIdx.x;
  const int bz = blockIdx.z;
  const half_t* A = Qh + (size_t)bz * SEQ * HID;
  const half_t* B = Kh + (size_t)bz * SEQ * HID;
  float* C = S + (size_t)bz * SEQ * SEQ;
  const int m0 = blockIdx.y * 128;
  const int n0 = blockIdx.x * 128;
  const int lane = t & 63, wid = t >> 6;
  const int wr = (wid >> 1) * 64, wc = (wid & 1) * 64;
  const int lrow = lane & 15, lks = lane >> 4;
  const int s1 = t, s2 = t + 256;
  const int ar1 = s1 >> 2, ac1 = (s1 & 3) * 8;
  const int ar2 = s2 >> 2, ac2 = (s2 & 3) * 8;

  f32x4 acc[4][4] = {};

  for (int k0 = 0; k0 < HID; k0 += 32) {
    __syncthreads();
    GLOAD_LDS16(A + (size_t)(m0 + ar1) * HID + k0 + ac1, &sA[s1 * 8]);
    GLOAD_LDS16(A + (size_t)(m0 + ar2) * HID + k0 + ac2, &sA[s2 * 8]);
    GLOAD_LDS16(B + (size_t)(n0 + ar1) * HID + k0 + ac1, &sB[s1 * 8]);
    GLOAD_LDS16(B + (size_t)(n0 + ar2) * HID + k0 + ac2, &sB[s2 * 8]);
    __syncthreads();
    half8 a[4], b[4];
#pragma unroll
    for (int m = 0; m < 4; ++m)
      a[m] = *reinterpret_cast<const half8*>(&sA[(wr + m * 16 + lrow) * 32 + lks * 8]);
#pragma unroll
    for (int n = 0; n < 4; ++n)
      b[n] = *reinterpret_cast<const half8*>(&sB[(wc + n * 16 + lrow) * 32 + lks * 8]);
#pragma unroll
    for (int m = 0; m < 4; ++m)
#pragma unroll
      for (int n = 0; n < 4; ++n)
        acc[m][n] = __builtin_amdgcn_mfma_f32_16x16x32_f16(a[m], b[n], acc[m][n], 0, 0, 0);
  }

  // raw score write
#pragma unroll
  for (int m = 0; m < 4; ++m)
#pragma unroll
    for (int n = 0; n < 4; ++n)
#pragma unroll
      for (int r = 0; r < 4; ++r)
        C[(size_t)(m0 + wr + m * 16 + lks * 4 + r) * SEQ + (n0 + wc + n * 16 + lrow)] =
            acc[m][n][r];

  // per-tile softmax partials
#pragma unroll
  for (int m = 0; m < 4; ++m) {
#pragma unroll
    for (int r = 0; r < 4; ++r) {
      float mx = fmaxf(fmaxf(acc[m][0][r], acc[m][1][r]),
                       fmaxf(acc[m][2][r], acc[m][3][r]));
      mx = fmaxf(mx, __shfl_xor(mx, 1));
      mx = fmaxf(mx, __shfl_xor(mx, 2));
      mx = fmaxf(mx, __shfl_xor(mx, 4));
      mx = fmaxf(mx, __shfl_xor(mx, 8));
      float s = expf(acc[m][0][r] - mx) + expf(acc[m][1][r] - mx) +
                expf(acc[m][2][r] - mx) + expf(acc[m][3][r] - mx);
      s += __shfl_xor(s, 1);
      s += __shfl_xor(s, 2);
      s += __shfl_xor(s, 4);
      s += __shfl_xor(s, 8);
      if (lrow == 0) {
        const int rr = wr + m * 16 + lks * 4 + r;
        lm[wid & 1][rr] = mx;
        ls[wid & 1][rr] = s;
      }
    }
  }
  __syncthreads();
  if (t < 128) {
    const float m0v = lm[0][t], m1v = lm[1][t];
    const float M = fmaxf(m0v, m1v);
    const float L = ls[0][t] * expf(m0v - M) + ls[1][t] * expf(m1v - M);
    part[(size_t)(bz * SEQ + m0 + t) * 32 + blockIdx.x] = make_float2(M, L);
  }
}

// ---------------- merge 32 per-tile partials per row -> (rowmax, 1/rowsum) --------
__global__ void k_lred(const float2* __restrict__ part, float2* __restrict__ stats) {
  const int row = blockIdx.x * 256 + threadIdx.x;  // [0, NB*SEQ)
  const float2* p = part + (size_t)row * 32;
  float M = -3.4028235e38f;
#pragma unroll
  for (int i = 0; i < 32; ++i) M = fmaxf(M, p[i].x);
  float L = 0.f;
#pragma unroll
  for (int i = 0; i < 32; ++i) L += p[i].y * expf(p[i].x - M);
  stats[row] = make_float2(M, 1.0f / L);
}

// ---------------- fused: normalize attn in-place + opt = attn @ V ----------------
// BM=32, BN=512 (full N), K-chunk=64. V fragments loaded DIRECTLY global->reg
// (L2-resident per XCD; no sB, no gload_lds, no vmcnt-coupled barrier).
// Only a tiny 2x4KB double-buffered sA holds the exp'd P tile (128B rows,
// 8-granule XOR swizzle - the pattern that measured 0 conflicts in R2).
__launch_bounds__(512, 4)
__global__ void k_pvn(float* __restrict__ P, const half_t* __restrict__ Vt,
                      const float2* __restrict__ stats, float* __restrict__ O) {
  __shared__ half_t sA[2][32 * 64];  // 2 x 4 KB
  const int t = threadIdx.x;

  // bijective XCD swizzle: 512 blocks, 64 per XCD; XCD pair handles one batch
  const int bid = blockIdx.x;
  const int sw = (bid & 7) * 64 + (bid >> 3);
  const int bz = sw >> 7;
  const int m0 = (sw & 127) * 32;

  float* Pb = P + (size_t)bz * SEQ * SEQ;
  const half_t* Vb = Vt + (size_t)bz * HID * SEQ;
  float* Ob = O + (size_t)bz * SEQ * HID;

  const int lane = t & 63, wid = t >> 6;
  const int lrow = lane & 15, lks = lane >> 4;

  // ---- P staging map: thread t handles float4 at (prow, pcol..pcol+3) of 32x64 tile
  const int prow = t >> 4;          // 0..31
  const int pcol = (t & 15) * 4;    // 0..60
  const float2 st = stats[(size_t)bz * SEQ + m0 + prow];
  const float mrow = st.x, invl = st.y;
  // swizzled sA f16 index for the 4-element (8B) write
  const int aswz = prow * 64 + ((((t & 15) >> 1) ^ (prow & 7)) << 3) + (t & 1) * 4;
  float* const Prow = Pb + (size_t)(m0 + prow) * SEQ + pcol;

  // ---- a-frag read offsets (swizzled): frag(m,kk): row=m*16+lrow, granule=kk*4+lks
  int aoff[2][2];
#pragma unroll
  for (int m = 0; m < 2; ++m)
#pragma unroll
    for (int kk = 0; kk < 2; ++kk) {
      const int row = m * 16 + lrow;
      aoff[m][kk] = row * 64 + (((kk * 4 + lks) ^ (row & 7)) << 3);
    }

  // ---- b-frag global base: frag(n): Vt row = wid*64 + n*16 + lrow
  const half_t* vbase[4];
#pragma unroll
  for (int n = 0; n < 4; ++n)
    vbase[n] = Vb + (size_t)(wid * 64 + n * 16 + lrow) * SEQ + lks * 8;

  f32x4 acc[2][4] = {};

  // ---- prologue: stage chunk 0 ----
  {
    float4 v = *reinterpret_cast<const float4*>(Prow);
    v.x = expf(v.x - mrow) * invl;
    v.y = expf(v.y - mrow) * invl;
    v.z = expf(v.z - mrow) * invl;
    v.w = expf(v.w - mrow) * invl;
    *reinterpret_cast<float4*>(Prow) = v;  // normalized attn, in place
    union { half_t h[4]; unsigned long long u; } cv;
    cv.h[0] = (half_t)v.x; cv.h[1] = (half_t)v.y;
    cv.h[2] = (half_t)v.z; cv.h[3] = (half_t)v.w;
    *reinterpret_cast<unsigned long long*>(&sA[0][aswz]) = cv.u;
  }
  __syncthreads();

  int cur = 0;
  for (int c = 0; c < SEQ / 64; ++c) {
    const int k0 = c * 64;
    // early-load next chunk's raw P (latency hides under this chunk's MFMA)
    float4 pv;
    if (c < SEQ / 64 - 1)
      pv = *reinterpret_cast<const float4*>(Prow + k0 + 64);

    // kk = 0
    {
      half8 b[4], a[2];
#pragma unroll
      for (int n = 0; n < 4; ++n)
        b[n] = *reinterpret_cast<const half8*>(vbase[n] + k0);
#pragma unroll
      for (int m = 0; m < 2; ++m)
        a[m] = *reinterpret_cast<const half8*>(&sA[cur][aoff[m][0]]);
#pragma unroll
      for (int m = 0; m < 2; ++m)
#pragma unroll
        for (int n = 0; n < 4; ++n)
          acc[m][n] = __builtin_amdgcn_mfma_f32_16x16x32_f16(a[m], b[n], acc[m][n], 0, 0, 0);
    }
    // kk = 1
    {
      half8 b[4], a[2];
#pragma unroll
      for (int n = 0; n < 4; ++n)
        b[n] = *reinterpret_cast<const half8*>(vbase[n] + k0 + 32);
#pragma unroll
      for (int m = 0; m < 2; ++m)
        a[m] = *reinterpret_cast<const half8*>(&sA[cur][aoff[m][1]]);
#pragma unroll
      for (int m = 0; m < 2; ++m)
#pragma unroll
        for (int n = 0; n < 4; ++n)
          acc[m][n] = __builtin_amdgcn_mfma_f32_16x16x32_f16(a[m], b[n], acc[m][n], 0, 0, 0);
    }

    // finish next chunk's P: exp, in-place store, stage into sA[nxt]
    if (c < SEQ / 64 - 1) {
      pv.x = expf(pv.x - mrow) * invl;
      pv.y = expf(pv.y - mrow) * invl;
      pv.z = expf(pv.z - mrow) * invl;
      pv.w = expf(pv.w - mrow) * invl;
      *reinterpret_cast<float4*>(Prow + k0 + 64) = pv;
      union { half_t h[4]; unsigned long long u; } cv;
      cv.h[0] = (half_t)pv.x; cv.h[1] = (half_t)pv.y;
      cv.h[2] = (half_t)pv.z; cv.h[3] = (half_t)pv.w;
      *reinterpret_cast<unsigned long long*>(&sA[cur ^ 1][aswz]) = cv.u;
      __syncthreads();
      cur ^= 1;
    }
  }

#pragma unroll
  for (int m = 0; m < 2; ++m)
#pragma unroll
    for (int n = 0; n < 4; ++n)
#pragma unroll
      for (int r = 0; r < 4; ++r)
        Ob[(size_t)(m0 + m * 16 + lks * 4 + r) * HID + (wid * 64 + n * 16 + lrow)] =
            acc[m][n][r];
}

extern "C" void kernel_launch(void* const* d_in, const int* in_sizes, int n_in,
                              void* d_out, int out_size, void* d_ws, size_t ws_size,
                              hipStream_t stream) {
  const float* x = (const float*)d_in[0];     // [4,4096,512]
  const float* W = (const float*)d_in[1];     // [512,1536]
  const float* bias = (const float*)d_in[2];  // [1536]
  float* opt = (float*)d_out;                        // [4*4096*512]
  float* attn = opt + (size_t)NB * SEQ * HID;        // [4*4096*4096]

  half_t* xh = (half_t*)d_ws;                        // 16384*512
  half_t* Wt = xh + (size_t)NB * SEQ * HID;          // 1536*512
  half_t* Qh = Wt + (size_t)N3 * HID;                // 16384*512 (scale folded)
  half_t* Kh = Qh + (size_t)NB * SEQ * HID;          // 16384*512
  half_t* Vt = Kh + (size_t)NB * SEQ * HID;          // 4*[512][4096] transposed
  float2* part = (float2*)(Vt + (size_t)NB * HID * SEQ);  // [16384][32]
  float2* stats = part + (size_t)NB * SEQ * 32;           // [16384]

  k_cvt<<<2048, 256, 0, stream>>>(x, xh, NB * SEQ * HID / 4);
  k_tw<<<dim3(N3 / 64, HID / 64), 256, 0, stream>>>(W, Wt);
  k_qkv<<<dim3(N3 / 128, NB * SEQ / 128), 256, 0, stream>>>(xh, Wt, bias, Qh, Kh, Vt);
  k_qk<<<dim3(SEQ / 128, SEQ / 128, NB), 256, 0, stream>>>(Qh, Kh, attn, part);
  k_lred<<<NB * SEQ / 256, 256, 0, stream>>>(part, stats);
  k_pvn<<<512, 512, 0, stream>>>(attn, Vt, stats, opt);
}

// Round 6
// 492.654 us; speedup vs baseline: 1.1410x; 1.1410x over previous
//
#include <hip/hip_runtime.h>

#define SEQ 4096
#define HID 512
#define NB  4
#define N3  1536
#define LOG2E 1.4426950408889634f

typedef _Float16 half_t;
typedef __attribute__((ext_vector_type(8))) _Float16 half8;
typedef __attribute__((ext_vector_type(4))) float f32x4;

#define GLOAD_LDS16(gp, lp) __builtin_amdgcn_global_load_lds((gp), (lp), 16, 0, 0)

// ---------------- convert x (f32) -> f16 ----------------
__global__ void k_cvt(const float* __restrict__ x, half_t* __restrict__ xh, int n4) {
  int i = blockIdx.x * blockDim.x + threadIdx.x;
  int stride = gridDim.x * blockDim.x;
  for (; i < n4; i += stride) {
    float4 v = reinterpret_cast<const float4*>(x)[i];
    union { half_t h[4]; short4 s; } u;
    u.h[0] = (half_t)v.x; u.h[1] = (half_t)v.y;
    u.h[2] = (half_t)v.z; u.h[3] = (half_t)v.w;
    reinterpret_cast<short4*>(xh)[i] = u.s;
  }
}

// ---------------- W [512][1536] f32 -> Wt [1536][512] f16 ----------------
__global__ void k_tw(const float* __restrict__ W, half_t* __restrict__ Wt) {
  __shared__ half_t tile[64][65];
  const int n0 = blockIdx.x * 64;
  const int k0 = blockIdx.y * 64;
  const int tx = threadIdx.x & 63, ty = threadIdx.x >> 6;
#pragma unroll
  for (int i = 0; i < 64; i += 4)
    tile[ty + i][tx] = (half_t)W[(size_t)(k0 + ty + i) * N3 + n0 + tx];
  __syncthreads();
#pragma unroll
  for (int i = 0; i < 64; i += 4)
    Wt[(size_t)(n0 + ty + i) * HID + k0 + tx] = tile[tx][ty + i];
}

// ---------------- QKV projection GEMM ----------------
__launch_bounds__(256)
__global__ void k_qkv(const half_t* __restrict__ xh, const half_t* __restrict__ Wt,
                      const float* __restrict__ bias,
                      half_t* __restrict__ Qh, half_t* __restrict__ Kh,
                      half_t* __restrict__ Vt) {
  __shared__ half_t sA[128 * 32];
  __shared__ half_t sB[128 * 32];
  const int t = threadIdx.x;
  const int m0 = blockIdx.y * 128;
  const int n0 = blockIdx.x * 128;
  const int lane = t & 63, wid = t >> 6;
  const int wr = (wid >> 1) * 64, wc = (wid & 1) * 64;
  const int lrow = lane & 15, lks = lane >> 4;
  const int s1 = t, s2 = t + 256;
  const int ar1 = s1 >> 2, ac1 = (s1 & 3) * 8;
  const int ar2 = s2 >> 2, ac2 = (s2 & 3) * 8;

  f32x4 acc[4][4] = {};

  for (int k0 = 0; k0 < HID; k0 += 32) {
    __syncthreads();
    GLOAD_LDS16(xh + (size_t)(m0 + ar1) * HID + k0 + ac1, &sA[s1 * 8]);
    GLOAD_LDS16(xh + (size_t)(m0 + ar2) * HID + k0 + ac2, &sA[s2 * 8]);
    GLOAD_LDS16(Wt + (size_t)(n0 + ar1) * HID + k0 + ac1, &sB[s1 * 8]);
    GLOAD_LDS16(Wt + (size_t)(n0 + ar2) * HID + k0 + ac2, &sB[s2 * 8]);
    __syncthreads();
    half8 a[4], b[4];
#pragma unroll
    for (int m = 0; m < 4; ++m)
      a[m] = *reinterpret_cast<const half8*>(&sA[(wr + m * 16 + lrow) * 32 + lks * 8]);
#pragma unroll
    for (int n = 0; n < 4; ++n)
      b[n] = *reinterpret_cast<const half8*>(&sB[(wc + n * 16 + lrow) * 32 + lks * 8]);
#pragma unroll
    for (int m = 0; m < 4; ++m)
#pragma unroll
      for (int n = 0; n < 4; ++n)
        acc[m][n] = __builtin_amdgcn_mfma_f32_16x16x32_f16(a[m], b[n], acc[m][n], 0, 0, 0);
  }

  const float scale = 0.04419417382415922f;  // 1/sqrt(512)
  const int region = n0 >> 9;  // 0=Q, 1=K, 2=V (uniform per block)
#pragma unroll
  for (int m = 0; m < 4; ++m) {
#pragma unroll
    for (int n = 0; n < 4; ++n) {
      const int col = n0 + wc + n * 16 + lrow;
#pragma unroll
      for (int r = 0; r < 4; ++r) {
        const int row = m0 + wr + m * 16 + lks * 4 + r;
        float v = acc[m][n][r] + bias[col];
        if (region == 0) {
          Qh[(size_t)row * HID + col] = (half_t)(v * scale);
        } else if (region == 1) {
          Kh[(size_t)row * HID + (col - 512)] = (half_t)v;
        } else {
          const int bb = row >> 12, ml = row & (SEQ - 1);
          Vt[((size_t)bb * HID + (col - 1024)) * SEQ + ml] = (half_t)v;
        }
      }
    }
  }
}

// ---------------- repack Vt [b][h][s] -> Vf MFMA-fragment tiles ----------------
// Tile (b, kc, hg) = 512 f16 contiguous: lane l, elem e = V[hg*16+(l&15)][kc*32+(l>>4)*8+e]
__global__ void k_vrep(const half_t* __restrict__ Vt, half_t* __restrict__ Vf) {
  const int g = blockIdx.x * 256 + threadIdx.x;   // one half8 per thread
  const int tile = g >> 6, l = g & 63;
  const int bb = tile >> 12;
  const int kc = (tile >> 5) & 127;
  const int hg = tile & 31;
  const int h = hg * 16 + (l & 15);
  const int s = kc * 32 + (l >> 4) * 8;
  half8 v = *reinterpret_cast<const half8*>(&Vt[((size_t)bb * HID + h) * SEQ + s]);
  *reinterpret_cast<half8*>(&Vf[(size_t)tile * 512 + l * 8]) = v;
}

// ---------------- scores = Q @ K^T, plus per-tile softmax partials ----------------
__launch_bounds__(256)
__global__ void k_qk(const half_t* __restrict__ Qh, const half_t* __restrict__ Kh,
                     float* __restrict__ S, float2* __restrict__ part) {
  __shared__ half_t sA[128 * 32];
  __shared__ half_t sB[128 * 32];
  __shared__ float lm[2][128], ls[2][128];
  const int t = threadIdx.x;
  const int bz = blockIdx.z;
  const half_t* A = Qh + (size_t)bz * SEQ * HID;
  const half_t* B = Kh + (size_t)bz * SEQ * HID;
  float* C = S + (size_t)bz * SEQ * SEQ;
  const int m0 = blockIdx.y * 128;
  const int n0 = blockIdx.x * 128;
  const int lane = t & 63, wid = t >> 6;
  const int wr = (wid >> 1) * 64, wc = (wid & 1) * 64;
  const int lrow = lane & 15, lks = lane >> 4;
  const int s1 = t, s2 = t + 256;
  const int ar1 = s1 >> 2, ac1 = (s1 & 3) * 8;
  const int ar2 = s2 >> 2, ac2 = (s2 & 3) * 8;

  f32x4 acc[4][4] = {};

  for (int k0 = 0; k0 < HID; k0 += 32) {
    __syncthreads();
    GLOAD_LDS16(A + (size_t)(m0 + ar1) * HID + k0 + ac1, &sA[s1 * 8]);
    GLOAD_LDS16(A + (size_t)(m0 + ar2) * HID + k0 + ac2, &sA[s2 * 8]);
    GLOAD_LDS16(B + (size_t)(n0 + ar1) * HID + k0 + ac1, &sB[s1 * 8]);
    GLOAD_LDS16(B + (size_t)(n0 + ar2) * HID + k0 + ac2, &sB[s2 * 8]);
    __syncthreads();
    half8 a[4], b[4];
#pragma unroll
    for (int m = 0; m < 4; ++m)
      a[m] = *reinterpret_cast<const half8*>(&sA[(wr + m * 16 + lrow) * 32 + lks * 8]);
#pragma unroll
    for (int n = 0; n < 4; ++n)
      b[n] = *reinterpret_cast<const half8*>(&sB[(wc + n * 16 + lrow) * 32 + lks * 8]);
#pragma unroll
    for (int m = 0; m < 4; ++m)
#pragma unroll
      for (int n = 0; n < 4; ++n)
        acc[m][n] = __builtin_amdgcn_mfma_f32_16x16x32_f16(a[m], b[n], acc[m][n], 0, 0, 0);
  }

  // raw score write
#pragma unroll
  for (int m = 0; m < 4; ++m)
#pragma unroll
    for (int n = 0; n < 4; ++n)
#pragma unroll
      for (int r = 0; r < 4; ++r)
        C[(size_t)(m0 + wr + m * 16 + lks * 4 + r) * SEQ + (n0 + wc + n * 16 + lrow)] =
            acc[m][n][r];

  // per-tile softmax partials
#pragma unroll
  for (int m = 0; m < 4; ++m) {
#pragma unroll
    for (int r = 0; r < 4; ++r) {
      float mx = fmaxf(fmaxf(acc[m][0][r], acc[m][1][r]),
                       fmaxf(acc[m][2][r], acc[m][3][r]));
      mx = fmaxf(mx, __shfl_xor(mx, 1));
      mx = fmaxf(mx, __shfl_xor(mx, 2));
      mx = fmaxf(mx, __shfl_xor(mx, 4));
      mx = fmaxf(mx, __shfl_xor(mx, 8));
      float s = expf(acc[m][0][r] - mx) + expf(acc[m][1][r] - mx) +
                expf(acc[m][2][r] - mx) + expf(acc[m][3][r] - mx);
      s += __shfl_xor(s, 1);
      s += __shfl_xor(s, 2);
      s += __shfl_xor(s, 4);
      s += __shfl_xor(s, 8);
      if (lrow == 0) {
        const int rr = wr + m * 16 + lks * 4 + r;
        lm[wid & 1][rr] = mx;
        ls[wid & 1][rr] = s;
      }
    }
  }
  __syncthreads();
  if (t < 128) {
    const float m0v = lm[0][t], m1v = lm[1][t];
    const float M = fmaxf(m0v, m1v);
    const float L = ls[0][t] * expf(m0v - M) + ls[1][t] * expf(m1v - M);
    part[(size_t)(bz * SEQ + m0 + t) * 32 + blockIdx.x] = make_float2(M, L);
  }
}

// ---------------- merge 32 per-tile partials per row -> (rowmax, 1/rowsum) --------
__global__ void k_lred(const float2* __restrict__ part, float2* __restrict__ stats) {
  const int row = blockIdx.x * 256 + threadIdx.x;  // [0, NB*SEQ)
  const float2* p = part + (size_t)row * 32;
  float M = -3.4028235e38f;
#pragma unroll
  for (int i = 0; i < 32; ++i) M = fmaxf(M, p[i].x);
  float L = 0.f;
#pragma unroll
  for (int i = 0; i < 32; ++i) L += p[i].y * expf(p[i].x - M);
  stats[row] = make_float2(M, 1.0f / L);
}

// ---------------- fused: normalize attn in-place + opt = attn @ V ----------------
// BM=32, BN=512, BK=64. V via fragment-packed Vf (1KB contiguous per b-frag load).
// Raw s_barrier + lgkmcnt(0)-only (no vmcnt drain); depth-2 P prefetch with static
// register names (2-unrolled loop); P loads issued LAST in vmem order each iter.
__launch_bounds__(512, 4)
__global__ void k_pvn(float* __restrict__ P, const half_t* __restrict__ Vf,
                      const float2* __restrict__ stats, float* __restrict__ O) {
  __shared__ half_t sA[2][32 * 64];  // 2 x 4 KB, XOR-swizzled (R2-verified pattern)
  const int t = threadIdx.x;

  // bijective XCD swizzle: 512 blocks, 64 per XCD
  const int bid = blockIdx.x;
  const int sw = (bid & 7) * 64 + (bid >> 3);
  const int bz = sw >> 7;
  const int m0 = (sw & 127) * 32;

  float* Pb = P + (size_t)bz * SEQ * SEQ;
  const half_t* Vfb = Vf + (size_t)bz * 128 * 32 * 512;
  float* Ob = O + (size_t)bz * SEQ * HID;

  const int lane = t & 63, wid = t >> 6;
  const int lrow = lane & 15, lks = lane >> 4;

  // P staging map: thread t handles float4 at (prow, pcol..pcol+3) of the 32x64 tile
  const int prow = t >> 4;          // 0..31
  const float2 st = stats[(size_t)bz * SEQ + m0 + prow];
  const float mrow = st.x, invl = st.y;
  const int aswz = prow * 64 + ((((t & 15) >> 1) ^ (prow & 7)) << 3) + (t & 1) * 4;
  float* const Prow = Pb + (size_t)(m0 + prow) * SEQ + (t & 15) * 4;

  // a-frag swizzled read offsets
  int aoff[2][2];
#pragma unroll
  for (int m = 0; m < 2; ++m)
#pragma unroll
    for (int kk = 0; kk < 2; ++kk) {
      const int row = m * 16 + lrow;
      aoff[m][kk] = row * 64 + (((kk * 4 + lks) ^ (row & 7)) << 3);
    }

  f32x4 acc[2][4] = {};

#define PV_STAGE(BUF, E)                                                     \
  {                                                                          \
    union { half_t h[4]; unsigned long long u; } cv;                         \
    cv.h[0] = (half_t)(E).x; cv.h[1] = (half_t)(E).y;                        \
    cv.h[2] = (half_t)(E).z; cv.h[3] = (half_t)(E).w;                        \
    *reinterpret_cast<unsigned long long*>(&sA[BUF][aswz]) = cv.u;           \
  }

#define PV_EXP(V, E)                                                         \
  {                                                                          \
    (E).x = exp2f(((V).x - mrow) * LOG2E) * invl;                            \
    (E).y = exp2f(((V).y - mrow) * LOG2E) * invl;                            \
    (E).z = exp2f(((V).z - mrow) * LOG2E) * invl;                            \
    (E).w = exp2f(((V).w - mrow) * LOG2E) * invl;                            \
  }

#define PV_MFMA(CUR, CC)                                                     \
  _Pragma("unroll")                                                          \
  for (int kk = 0; kk < 2; ++kk) {                                           \
    const int kc = (CC) * 2 + kk;                                            \
    half8 b[4], a[2];                                                        \
    _Pragma("unroll")                                                        \
    for (int n = 0; n < 4; ++n)                                              \
      b[n] = *reinterpret_cast<const half8*>(                                \
          Vfb + ((size_t)kc * 32 + wid * 4 + n) * 512 + lane * 8);           \
    _Pragma("unroll")                                                        \
    for (int m = 0; m < 2; ++m)                                              \
      a[m] = *reinterpret_cast<const half8*>(&sA[CUR][aoff[m][kk]]);         \
    _Pragma("unroll")                                                        \
    for (int m = 0; m < 2; ++m)                                              \
      _Pragma("unroll")                                                      \
      for (int n = 0; n < 4; ++n)                                            \
        acc[m][n] = __builtin_amdgcn_mfma_f32_16x16x32_f16(a[m], b[n],       \
                                                           acc[m][n], 0, 0, 0); \
  }

#define PV_BARRIER()                                                         \
  asm volatile("s_waitcnt lgkmcnt(0)" ::: "memory");                         \
  __builtin_amdgcn_sched_barrier(0);                                         \
  __builtin_amdgcn_s_barrier();

  // SUB: compute chunk CC from sA[CUR]; stage chunk CC+1 from PVOLD into sA[CUR^1];
  //      load chunk CC+2 -> PVNEW (issued last); barrier.
#define PV_SUB(CUR, PVOLD, PVNEW, CC)                                        \
  {                                                                          \
    float4 e;                                                                \
    const bool do_stage = (CC) + 1 < 64;                                     \
    const bool do_load = (CC) + 2 < 64;                                      \
    if (do_stage) {                                                          \
      PV_EXP(PVOLD, e);                                                      \
      PV_STAGE((CUR) ^ 1, e);                                                \
    }                                                                        \
    PV_MFMA(CUR, CC)                                                         \
    if (do_stage)                                                            \
      *reinterpret_cast<float4*>(Prow + ((CC) + 1) * 64) = e;                \
    if (do_load)                                                             \
      PVNEW = *reinterpret_cast<const float4*>(Prow + ((CC) + 2) * 64);      \
    PV_BARRIER();                                                            \
  }

  float4 pvOdd, pvEven;
  // ---- prologue: stage chunk 0 directly; load chunk 1 raw ----
  {
    float4 v = *reinterpret_cast<const float4*>(Prow);
    float4 e;
    PV_EXP(v, e);
    PV_STAGE(0, e);
    *reinterpret_cast<float4*>(Prow) = e;
    pvOdd = *reinterpret_cast<const float4*>(Prow + 64);
    PV_BARRIER();
  }

  for (int c = 0; c < 64; c += 2) {
    PV_SUB(0, pvOdd, pvEven, c);
    PV_SUB(1, pvEven, pvOdd, c + 1);
  }

#pragma unroll
  for (int m = 0; m < 2; ++m)
#pragma unroll
    for (int n = 0; n < 4; ++n)
#pragma unroll
      for (int r = 0; r < 4; ++r)
        Ob[(size_t)(m0 + m * 16 + lks * 4 + r) * HID + (wid * 64 + n * 16 + lrow)] =
            acc[m][n][r];
}

extern "C" void kernel_launch(void* const* d_in, const int* in_sizes, int n_in,
                              void* d_out, int out_size, void* d_ws, size_t ws_size,
                              hipStream_t stream) {
  const float* x = (const float*)d_in[0];     // [4,4096,512]
  const float* W = (const float*)d_in[1];     // [512,1536]
  const float* bias = (const float*)d_in[2];  // [1536]
  float* opt = (float*)d_out;                        // [4*4096*512]
  float* attn = opt + (size_t)NB * SEQ * HID;        // [4*4096*4096]

  half_t* xh = (half_t*)d_ws;                        // 16384*512
  half_t* Wt = xh + (size_t)NB * SEQ * HID;          // 1536*512
  half_t* Qh = Wt + (size_t)N3 * HID;                // 16384*512 (scale folded)
  half_t* Kh = Qh + (size_t)NB * SEQ * HID;          // 16384*512
  half_t* Vt = Kh + (size_t)NB * SEQ * HID;          // 4*[512][4096] transposed
  half_t* Vf = Vt + (size_t)NB * HID * SEQ;          // fragment-packed V (16 MB)
  float2* part = (float2*)(Vf + (size_t)NB * HID * SEQ);  // [16384][32]
  float2* stats = part + (size_t)NB * SEQ * 32;           // [16384]

  k_cvt<<<2048, 256, 0, stream>>>(x, xh, NB * SEQ * HID / 4);
  k_tw<<<dim3(N3 / 64, HID / 64), 256, 0, stream>>>(W, Wt);
  k_qkv<<<dim3(N3 / 128, NB * SEQ / 128), 256, 0, stream>>>(xh, Wt, bias, Qh, Kh, Vt);
  k_vrep<<<NB * HID * SEQ / 8 / 256, 256, 0, stream>>>(Vt, Vf);
  k_qk<<<dim3(SEQ / 128, SEQ / 128, NB), 256, 0, stream>>>(Qh, Kh, attn, part);
  k_lred<<<NB * SEQ / 256, 256, 0, stream>>>(part, stats);
  k_pvn<<<512, 512, 0, stream>>>(attn, Vf, stats, opt);
}

// Round 7
// 490.160 us; speedup vs baseline: 1.1468x; 1.0051x over previous
//
#include <hip/hip_runtime.h>

#define SEQ 4096
#define HID 512
#define NB  4
#define N3  1536
#define LOG2E 1.4426950408889634f

typedef _Float16 half_t;
typedef __attribute__((ext_vector_type(8))) _Float16 half8;
typedef __attribute__((ext_vector_type(4))) float f32x4;

#define GLOAD_LDS16(gp, lp) __builtin_amdgcn_global_load_lds((gp), (lp), 16, 0, 0)

// ---------------- convert x (f32) -> f16 ----------------
__global__ void k_cvt(const float* __restrict__ x, half_t* __restrict__ xh, int n4) {
  int i = blockIdx.x * blockDim.x + threadIdx.x;
  int stride = gridDim.x * blockDim.x;
  for (; i < n4; i += stride) {
    float4 v = reinterpret_cast<const float4*>(x)[i];
    union { half_t h[4]; short4 s; } u;
    u.h[0] = (half_t)v.x; u.h[1] = (half_t)v.y;
    u.h[2] = (half_t)v.z; u.h[3] = (half_t)v.w;
    reinterpret_cast<short4*>(xh)[i] = u.s;
  }
}

// ---------------- W [512][1536] f32 -> Wt [1536][512] f16 ----------------
__global__ void k_tw(const float* __restrict__ W, half_t* __restrict__ Wt) {
  __shared__ half_t tile[64][65];
  const int n0 = blockIdx.x * 64;
  const int k0 = blockIdx.y * 64;
  const int tx = threadIdx.x & 63, ty = threadIdx.x >> 6;
#pragma unroll
  for (int i = 0; i < 64; i += 4)
    tile[ty + i][tx] = (half_t)W[(size_t)(k0 + ty + i) * N3 + n0 + tx];
  __syncthreads();
#pragma unroll
  for (int i = 0; i < 64; i += 4)
    Wt[(size_t)(n0 + ty + i) * HID + k0 + tx] = tile[tx][ty + i];
}

// ---------------- QKV projection GEMM ----------------
__launch_bounds__(256)
__global__ void k_qkv(const half_t* __restrict__ xh, const half_t* __restrict__ Wt,
                      const float* __restrict__ bias,
                      half_t* __restrict__ Qh, half_t* __restrict__ Kh,
                      half_t* __restrict__ Vt) {
  __shared__ half_t sA[128 * 32];
  __shared__ half_t sB[128 * 32];
  const int t = threadIdx.x;
  const int m0 = blockIdx.y * 128;
  const int n0 = blockIdx.x * 128;
  const int lane = t & 63, wid = t >> 6;
  const int wr = (wid >> 1) * 64, wc = (wid & 1) * 64;
  const int lrow = lane & 15, lks = lane >> 4;
  const int s1 = t, s2 = t + 256;
  const int ar1 = s1 >> 2, ac1 = (s1 & 3) * 8;
  const int ar2 = s2 >> 2, ac2 = (s2 & 3) * 8;

  f32x4 acc[4][4] = {};

  for (int k0 = 0; k0 < HID; k0 += 32) {
    __syncthreads();
    GLOAD_LDS16(xh + (size_t)(m0 + ar1) * HID + k0 + ac1, &sA[s1 * 8]);
    GLOAD_LDS16(xh + (size_t)(m0 + ar2) * HID + k0 + ac2, &sA[s2 * 8]);
    GLOAD_LDS16(Wt + (size_t)(n0 + ar1) * HID + k0 + ac1, &sB[s1 * 8]);
    GLOAD_LDS16(Wt + (size_t)(n0 + ar2) * HID + k0 + ac2, &sB[s2 * 8]);
    __syncthreads();
    half8 a[4], b[4];
#pragma unroll
    for (int m = 0; m < 4; ++m)
      a[m] = *reinterpret_cast<const half8*>(&sA[(wr + m * 16 + lrow) * 32 + lks * 8]);
#pragma unroll
    for (int n = 0; n < 4; ++n)
      b[n] = *reinterpret_cast<const half8*>(&sB[(wc + n * 16 + lrow) * 32 + lks * 8]);
#pragma unroll
    for (int m = 0; m < 4; ++m)
#pragma unroll
      for (int n = 0; n < 4; ++n)
        acc[m][n] = __builtin_amdgcn_mfma_f32_16x16x32_f16(a[m], b[n], acc[m][n], 0, 0, 0);
  }

  const float scale = 0.04419417382415922f;  // 1/sqrt(512)
  const int region = n0 >> 9;  // 0=Q, 1=K, 2=V (uniform per block)
#pragma unroll
  for (int m = 0; m < 4; ++m) {
#pragma unroll
    for (int n = 0; n < 4; ++n) {
      const int col = n0 + wc + n * 16 + lrow;
#pragma unroll
      for (int r = 0; r < 4; ++r) {
        const int row = m0 + wr + m * 16 + lks * 4 + r;
        float v = acc[m][n][r] + bias[col];
        if (region == 0) {
          Qh[(size_t)row * HID + col] = (half_t)(v * scale);
        } else if (region == 1) {
          Kh[(size_t)row * HID + (col - 512)] = (half_t)v;
        } else {
          const int bb = row >> 12, ml = row & (SEQ - 1);
          Vt[((size_t)bb * HID + (col - 1024)) * SEQ + ml] = (half_t)v;
        }
      }
    }
  }
}

// ---------------- repack Vt [b][h][s] -> Vf MFMA-fragment tiles ----------------
__global__ void k_vrep(const half_t* __restrict__ Vt, half_t* __restrict__ Vf) {
  const int g = blockIdx.x * 256 + threadIdx.x;   // one half8 per thread
  const int tile = g >> 6, l = g & 63;
  const int bb = tile >> 12;
  const int kc = (tile >> 5) & 127;
  const int hg = tile & 31;
  const int h = hg * 16 + (l & 15);
  const int s = kc * 32 + (l >> 4) * 8;
  half8 v = *reinterpret_cast<const half8*>(&Vt[((size_t)bb * HID + h) * SEQ + s]);
  *reinterpret_cast<half8*>(&Vf[(size_t)tile * 512 + l * 8]) = v;
}

// ---------------- scores = Q @ K^T, plus per-tile softmax partials ----------------
__launch_bounds__(256)
__global__ void k_qk(const half_t* __restrict__ Qh, const half_t* __restrict__ Kh,
                     float* __restrict__ S, float2* __restrict__ part) {
  __shared__ half_t sA[128 * 32];
  __shared__ half_t sB[128 * 32];
  __shared__ float lm[2][128], ls[2][128];
  const int t = threadIdx.x;
  const int bz = blockIdx.z;
  const half_t* A = Qh + (size_t)bz * SEQ * HID;
  const half_t* B = Kh + (size_t)bz * SEQ * HID;
  float* C = S + (size_t)bz * SEQ * SEQ;
  const int m0 = blockIdx.y * 128;
  const int n0 = blockIdx.x * 128;
  const int lane = t & 63, wid = t >> 6;
  const int wr = (wid >> 1) * 64, wc = (wid & 1) * 64;
  const int lrow = lane & 15, lks = lane >> 4;
  const int s1 = t, s2 = t + 256;
  const int ar1 = s1 >> 2, ac1 = (s1 & 3) * 8;
  const int ar2 = s2 >> 2, ac2 = (s2 & 3) * 8;

  f32x4 acc[4][4] = {};

  for (int k0 = 0; k0 < HID; k0 += 32) {
    __syncthreads();
    GLOAD_LDS16(A + (size_t)(m0 + ar1) * HID + k0 + ac1, &sA[s1 * 8]);
    GLOAD_LDS16(A + (size_t)(m0 + ar2) * HID + k0 + ac2, &sA[s2 * 8]);
    GLOAD_LDS16(B + (size_t)(n0 + ar1) * HID + k0 + ac1, &sB[s1 * 8]);
    GLOAD_LDS16(B + (size_t)(n0 + ar2) * HID + k0 + ac2, &sB[s2 * 8]);
    __syncthreads();
    half8 a[4], b[4];
#pragma unroll
    for (int m = 0; m < 4; ++m)
      a[m] = *reinterpret_cast<const half8*>(&sA[(wr + m * 16 + lrow) * 32 + lks * 8]);
#pragma unroll
    for (int n = 0; n < 4; ++n)
      b[n] = *reinterpret_cast<const half8*>(&sB[(wc + n * 16 + lrow) * 32 + lks * 8]);
#pragma unroll
    for (int m = 0; m < 4; ++m)
#pragma unroll
      for (int n = 0; n < 4; ++n)
        acc[m][n] = __builtin_amdgcn_mfma_f32_16x16x32_f16(a[m], b[n], acc[m][n], 0, 0, 0);
  }

  // raw score write
#pragma unroll
  for (int m = 0; m < 4; ++m)
#pragma unroll
    for (int n = 0; n < 4; ++n)
#pragma unroll
      for (int r = 0; r < 4; ++r)
        C[(size_t)(m0 + wr + m * 16 + lks * 4 + r) * SEQ + (n0 + wc + n * 16 + lrow)] =
            acc[m][n][r];

  // per-tile softmax partials
#pragma unroll
  for (int m = 0; m < 4; ++m) {
#pragma unroll
    for (int r = 0; r < 4; ++r) {
      float mx = fmaxf(fmaxf(acc[m][0][r], acc[m][1][r]),
                       fmaxf(acc[m][2][r], acc[m][3][r]));
      mx = fmaxf(mx, __shfl_xor(mx, 1));
      mx = fmaxf(mx, __shfl_xor(mx, 2));
      mx = fmaxf(mx, __shfl_xor(mx, 4));
      mx = fmaxf(mx, __shfl_xor(mx, 8));
      float s = expf(acc[m][0][r] - mx) + expf(acc[m][1][r] - mx) +
                expf(acc[m][2][r] - mx) + expf(acc[m][3][r] - mx);
      s += __shfl_xor(s, 1);
      s += __shfl_xor(s, 2);
      s += __shfl_xor(s, 4);
      s += __shfl_xor(s, 8);
      if (lrow == 0) {
        const int rr = wr + m * 16 + lks * 4 + r;
        lm[wid & 1][rr] = mx;
        ls[wid & 1][rr] = s;
      }
    }
  }
  __syncthreads();
  if (t < 128) {
    const float m0v = lm[0][t], m1v = lm[1][t];
    const float M = fmaxf(m0v, m1v);
    const float L = ls[0][t] * expf(m0v - M) + ls[1][t] * expf(m1v - M);
    part[(size_t)(bz * SEQ + m0 + t) * 32 + blockIdx.x] = make_float2(M, L);
  }
}

// ---------------- merge 32 per-tile partials per row -> (rowmax, 1/rowsum) --------
__global__ void k_lred(const float2* __restrict__ part, float2* __restrict__ stats) {
  const int row = blockIdx.x * 256 + threadIdx.x;  // [0, NB*SEQ)
  const float2* p = part + (size_t)row * 32;
  float M = -3.4028235e38f;
#pragma unroll
  for (int i = 0; i < 32; ++i) M = fmaxf(M, p[i].x);
  float L = 0.f;
#pragma unroll
  for (int i = 0; i < 32; ++i) L += p[i].y * expf(p[i].x - M);
  stats[row] = make_float2(M, 1.0f / L);
}

// ---------------- fused: normalize attn in-place + opt = attn @ V ----------------
// BM=32, BN=512, BK=64. V via fragment-packed Vf (contiguous per b-frag load).
// Raw P staged via global_load_lds into a 2x8KB LDS ring, issued AFTER the V
// loads each iter -> compiler's V-register waits are vmcnt(1), leaving the P
// stage in flight across barriers (never drained). P(c+1) consumed after the
// MFMA block behind an explicit vmcnt(1): in-order counter guarantees the
// older P stage has landed. Barriers are lgkm-only.
__launch_bounds__(512, 4)
__global__ void k_pvn(float* __restrict__ P, const half_t* __restrict__ Vf,
                      const float2* __restrict__ stats, float* __restrict__ O) {
  __shared__ half_t sA[2][32 * 64];   // exp'd f16 P chunk, XOR-swizzled (2 x 4 KB)
  __shared__ float praw[2][512 * 4];  // raw P staging ring (2 x 8 KB), linear by tid
  const int t = threadIdx.x;

  // bijective XCD swizzle: 512 blocks, 64 per XCD
  const int bid = blockIdx.x;
  const int sw = (bid & 7) * 64 + (bid >> 3);
  const int bz = sw >> 7;
  const int m0 = (sw & 127) * 32;

  float* Pb = P + (size_t)bz * SEQ * SEQ;
  const half_t* Vfb = Vf + (size_t)bz * 128 * 32 * 512;
  float* Ob = O + (size_t)bz * SEQ * HID;

  const int lane = t & 63, wid = t >> 6;
  const int lrow = lane & 15, lks = lane >> 4;

  // P map: thread t owns float4 at (prow, (t&15)*4 + c*64)
  const int prow = t >> 4;          // 0..31
  const float2 st = stats[(size_t)bz * SEQ + m0 + prow];
  const float mrow = st.x, invl = st.y;
  const int aswz = prow * 64 + ((((t & 15) >> 1) ^ (prow & 7)) << 3) + (t & 1) * 4;
  float* const Prow = Pb + (size_t)(m0 + prow) * SEQ + (t & 15) * 4;

  // a-frag swizzled read offsets
  int aoff[2][2];
#pragma unroll
  for (int m = 0; m < 2; ++m)
#pragma unroll
    for (int kk = 0; kk < 2; ++kk) {
      const int row = m * 16 + lrow;
      aoff[m][kk] = row * 64 + (((kk * 4 + lks) ^ (row & 7)) << 3);
    }

  f32x4 acc[2][4] = {};

#define PV_EXPSTAGE(BUF, V)                                                  \
  {                                                                          \
    (V).x = exp2f(((V).x - mrow) * LOG2E) * invl;                            \
    (V).y = exp2f(((V).y - mrow) * LOG2E) * invl;                            \
    (V).z = exp2f(((V).z - mrow) * LOG2E) * invl;                            \
    (V).w = exp2f(((V).w - mrow) * LOG2E) * invl;                            \
    union { half_t h[4]; unsigned long long u; } cv;                         \
    cv.h[0] = (half_t)(V).x; cv.h[1] = (half_t)(V).y;                        \
    cv.h[2] = (half_t)(V).z; cv.h[3] = (half_t)(V).w;                        \
    *reinterpret_cast<unsigned long long*>(&sA[BUF][aswz]) = cv.u;           \
  }

  // ---- prologue: chunk 0 direct; issue P(1) -> praw[1] ----
  {
    float4 v = *reinterpret_cast<const float4*>(Prow);
    PV_EXPSTAGE(0, v);
    *reinterpret_cast<float4*>(Prow) = v;  // normalized attn, in place
    GLOAD_LDS16(Prow + 64, &praw[1][t * 4]);
    asm volatile("s_waitcnt lgkmcnt(0)" ::: "memory");
    __builtin_amdgcn_sched_barrier(0);
    __builtin_amdgcn_s_barrier();
  }

  for (int c = 0; c < 64; ++c) {
    const int cur = c & 1;
    // V b-frag loads first (8 x 16B, contiguous, L2-resident)
    half8 b[2][4];
#pragma unroll
    for (int kk = 0; kk < 2; ++kk)
#pragma unroll
      for (int n = 0; n < 4; ++n)
        b[kk][n] = *reinterpret_cast<const half8*>(
            Vfb + ((size_t)(c * 2 + kk) * 32 + wid * 4 + n) * 512 + lane * 8);
    // P stage issued last -> V waits are vmcnt(1), P rides across the barrier
    if (c + 2 < 64)
      GLOAD_LDS16(Prow + (c + 2) * 64, &praw[c & 1][t * 4]);

    // MFMA (compiler waits vmcnt(1) for b)
#pragma unroll
    for (int kk = 0; kk < 2; ++kk) {
      half8 a[2];
#pragma unroll
      for (int m = 0; m < 2; ++m)
        a[m] = *reinterpret_cast<const half8*>(&sA[cur][aoff[m][kk]]);
#pragma unroll
      for (int m = 0; m < 2; ++m)
#pragma unroll
        for (int n = 0; n < 4; ++n)
          acc[m][n] = __builtin_amdgcn_mfma_f32_16x16x32_f16(a[m], b[kk][n],
                                                             acc[m][n], 0, 0, 0);
    }

    // consume P(c+1): older than everything issued this iter -> vmcnt(1) proves done
    if (c + 1 < 64) {
      asm volatile("s_waitcnt vmcnt(1)" ::: "memory");
      __builtin_amdgcn_sched_barrier(0);
      float4 v = *reinterpret_cast<const float4*>(&praw[(c + 1) & 1][t * 4]);
      PV_EXPSTAGE((c + 1) & 1, v);
      *reinterpret_cast<float4*>(Prow + (c + 1) * 64) = v;  // normalized attn
    }

    asm volatile("s_waitcnt lgkmcnt(0)" ::: "memory");
    __builtin_amdgcn_sched_barrier(0);
    __builtin_amdgcn_s_barrier();
  }

#pragma unroll
  for (int m = 0; m < 2; ++m)
#pragma unroll
    for (int n = 0; n < 4; ++n)
#pragma unroll
      for (int r = 0; r < 4; ++r)
        Ob[(size_t)(m0 + m * 16 + lks * 4 + r) * HID + (wid * 64 + n * 16 + lrow)] =
            acc[m][n][r];
}

extern "C" void kernel_launch(void* const* d_in, const int* in_sizes, int n_in,
                              void* d_out, int out_size, void* d_ws, size_t ws_size,
                              hipStream_t stream) {
  const float* x = (const float*)d_in[0];     // [4,4096,512]
  const float* W = (const float*)d_in[1];     // [512,1536]
  const float* bias = (const float*)d_in[2];  // [1536]
  float* opt = (float*)d_out;                        // [4*4096*512]
  float* attn = opt + (size_t)NB * SEQ * HID;        // [4*4096*4096]

  half_t* xh = (half_t*)d_ws;                        // 16384*512
  half_t* Wt = xh + (size_t)NB * SEQ * HID;          // 1536*512
  half_t* Qh = Wt + (size_t)N3 * HID;                // 16384*512 (scale folded)
  half_t* Kh = Qh + (size_t)NB * SEQ * HID;          // 16384*512
  half_t* Vt = Kh + (size_t)NB * SEQ * HID;          // 4*[512][4096] transposed
  half_t* Vf = Vt + (size_t)NB * HID * SEQ;          // fragment-packed V (16 MB)
  float2* part = (float2*)(Vf + (size_t)NB * HID * SEQ);  // [16384][32]
  float2* stats = part + (size_t)NB * SEQ * 32;           // [16384]

  k_cvt<<<2048, 256, 0, stream>>>(x, xh, NB * SEQ * HID / 4);
  k_tw<<<dim3(N3 / 64, HID / 64), 256, 0, stream>>>(W, Wt);
  k_qkv<<<dim3(N3 / 128, NB * SEQ / 128), 256, 0, stream>>>(xh, Wt, bias, Qh, Kh, Vt);
  k_vrep<<<NB * HID * SEQ / 8 / 256, 256, 0, stream>>>(Vt, Vf);
  k_qk<<<dim3(SEQ / 128, SEQ / 128, NB), 256, 0, stream>>>(Qh, Kh, attn, part);
  k_lred<<<NB * SEQ / 256, 256, 0, stream>>>(part, stats);
  k_pvn<<<512, 512, 0, stream>>>(attn, Vf, stats, opt);
}

// Round 8
// 397.106 us; speedup vs baseline: 1.4156x; 1.2343x over previous
//
#include <hip/hip_runtime.h>

#define SEQ 4096
#define HID 512
#define NB  4
#define N3  1536
#define LOG2E 1.4426950408889634f

typedef _Float16 half_t;
typedef __attribute__((ext_vector_type(8))) _Float16 half8;
typedef __attribute__((ext_vector_type(4))) float f32x4;

#define GLOAD_LDS16(gp, lp) __builtin_amdgcn_global_load_lds((gp), (lp), 16, 0, 0)

#define LGKM_BARRIER()                                                       \
  asm volatile("s_waitcnt lgkmcnt(0)" ::: "memory");                         \
  __builtin_amdgcn_sched_barrier(0);                                         \
  __builtin_amdgcn_s_barrier();

// ---------------- convert x (f32) -> f16 ----------------
__global__ void k_cvt(const float* __restrict__ x, half_t* __restrict__ xh, int n4) {
  int i = blockIdx.x * blockDim.x + threadIdx.x;
  int stride = gridDim.x * blockDim.x;
  for (; i < n4; i += stride) {
    float4 v = reinterpret_cast<const float4*>(x)[i];
    union { half_t h[4]; short4 s; } u;
    u.h[0] = (half_t)v.x; u.h[1] = (half_t)v.y;
    u.h[2] = (half_t)v.z; u.h[3] = (half_t)v.w;
    reinterpret_cast<short4*>(xh)[i] = u.s;
  }
}

// ---------------- W [512][1536] f32 -> Wt [1536][512] f16 ----------------
__global__ void k_tw(const float* __restrict__ W, half_t* __restrict__ Wt) {
  __shared__ half_t tile[64][65];
  const int n0 = blockIdx.x * 64;
  const int k0 = blockIdx.y * 64;
  const int tx = threadIdx.x & 63, ty = threadIdx.x >> 6;
#pragma unroll
  for (int i = 0; i < 64; i += 4)
    tile[ty + i][tx] = (half_t)W[(size_t)(k0 + ty + i) * N3 + n0 + tx];
  __syncthreads();
#pragma unroll
  for (int i = 0; i < 64; i += 4)
    Wt[(size_t)(n0 + ty + i) * HID + k0 + tx] = tile[tx][ty + i];
}

// ---------------- QKV projection GEMM ----------------
__launch_bounds__(256)
__global__ void k_qkv(const half_t* __restrict__ xh, const half_t* __restrict__ Wt,
                      const float* __restrict__ bias,
                      half_t* __restrict__ Qh, half_t* __restrict__ Kh,
                      half_t* __restrict__ Vt) {
  __shared__ half_t sA[128 * 32];
  __shared__ half_t sB[128 * 32];
  const int t = threadIdx.x;
  const int m0 = blockIdx.y * 128;
  const int n0 = blockIdx.x * 128;
  const int lane = t & 63, wid = t >> 6;
  const int wr = (wid >> 1) * 64, wc = (wid & 1) * 64;
  const int lrow = lane & 15, lks = lane >> 4;
  const int s1 = t, s2 = t + 256;
  const int ar1 = s1 >> 2, ac1 = (s1 & 3) * 8;
  const int ar2 = s2 >> 2, ac2 = (s2 & 3) * 8;

  f32x4 acc[4][4] = {};

  for (int k0 = 0; k0 < HID; k0 += 32) {
    __syncthreads();
    GLOAD_LDS16(xh + (size_t)(m0 + ar1) * HID + k0 + ac1, &sA[s1 * 8]);
    GLOAD_LDS16(xh + (size_t)(m0 + ar2) * HID + k0 + ac2, &sA[s2 * 8]);
    GLOAD_LDS16(Wt + (size_t)(n0 + ar1) * HID + k0 + ac1, &sB[s1 * 8]);
    GLOAD_LDS16(Wt + (size_t)(n0 + ar2) * HID + k0 + ac2, &sB[s2 * 8]);
    __syncthreads();
    half8 a[4], b[4];
#pragma unroll
    for (int m = 0; m < 4; ++m)
      a[m] = *reinterpret_cast<const half8*>(&sA[(wr + m * 16 + lrow) * 32 + lks * 8]);
#pragma unroll
    for (int n = 0; n < 4; ++n)
      b[n] = *reinterpret_cast<const half8*>(&sB[(wc + n * 16 + lrow) * 32 + lks * 8]);
#pragma unroll
    for (int m = 0; m < 4; ++m)
#pragma unroll
      for (int n = 0; n < 4; ++n)
        acc[m][n] = __builtin_amdgcn_mfma_f32_16x16x32_f16(a[m], b[n], acc[m][n], 0, 0, 0);
  }

  const float scale = 0.04419417382415922f;  // 1/sqrt(512)
  const int region = n0 >> 9;  // 0=Q, 1=K, 2=V (uniform per block)
#pragma unroll
  for (int m = 0; m < 4; ++m) {
#pragma unroll
    for (int n = 0; n < 4; ++n) {
      const int col = n0 + wc + n * 16 + lrow;
#pragma unroll
      for (int r = 0; r < 4; ++r) {
        const int row = m0 + wr + m * 16 + lks * 4 + r;
        float v = acc[m][n][r] + bias[col];
        if (region == 0) {
          Qh[(size_t)row * HID + col] = (half_t)(v * scale);
        } else if (region == 1) {
          Kh[(size_t)row * HID + (col - 512)] = (half_t)v;
        } else {
          const int bb = row >> 12, ml = row & (SEQ - 1);
          Vt[((size_t)bb * HID + (col - 1024)) * SEQ + ml] = (half_t)v;
        }
      }
    }
  }
}

// ---------------- repack Vt [b][h][s] -> Vf MFMA-fragment tiles ----------------
__global__ void k_vrep(const half_t* __restrict__ Vt, half_t* __restrict__ Vf) {
  const int g = blockIdx.x * 256 + threadIdx.x;   // one half8 per thread
  const int tile = g >> 6, l = g & 63;
  const int bb = tile >> 12;
  const int kc = (tile >> 5) & 127;
  const int hg = tile & 31;
  const int h = hg * 16 + (l & 15);
  const int s = kc * 32 + (l >> 4) * 8;
  half8 v = *reinterpret_cast<const half8*>(&Vt[((size_t)bb * HID + h) * SEQ + s]);
  *reinterpret_cast<half8*>(&Vf[(size_t)tile * 512 + l * 8]) = v;
}

// ---------------- scores = Q @ K^T -> f16 Sh (packed in attn region) + partials --
// Sh(b,row,col) lives at byte offset 8192+2*col inside attn row (b,row)'s 16KB.
__launch_bounds__(256)
__global__ void k_qk(const half_t* __restrict__ Qh, const half_t* __restrict__ Kh,
                     float* __restrict__ S, float2* __restrict__ part) {
  __shared__ half_t sA[128 * 32];
  __shared__ half_t sB[128 * 32];
  __shared__ float lm[2][128], ls[2][128];
  const int t = threadIdx.x;
  const int bz = blockIdx.z;
  const half_t* A = Qh + (size_t)bz * SEQ * HID;
  const half_t* B = Kh + (size_t)bz * SEQ * HID;
  half_t* Ch = (half_t*)(S + (size_t)bz * SEQ * SEQ);
  const int m0 = blockIdx.y * 128;
  const int n0 = blockIdx.x * 128;
  const int lane = t & 63, wid = t >> 6;
  const int wr = (wid >> 1) * 64, wc = (wid & 1) * 64;
  const int lrow = lane & 15, lks = lane >> 4;
  const int s1 = t, s2 = t + 256;
  const int ar1 = s1 >> 2, ac1 = (s1 & 3) * 8;
  const int ar2 = s2 >> 2, ac2 = (s2 & 3) * 8;

  f32x4 acc[4][4] = {};

  for (int k0 = 0; k0 < HID; k0 += 32) {
    __syncthreads();
    GLOAD_LDS16(A + (size_t)(m0 + ar1) * HID + k0 + ac1, &sA[s1 * 8]);
    GLOAD_LDS16(A + (size_t)(m0 + ar2) * HID + k0 + ac2, &sA[s2 * 8]);
    GLOAD_LDS16(B + (size_t)(n0 + ar1) * HID + k0 + ac1, &sB[s1 * 8]);
    GLOAD_LDS16(B + (size_t)(n0 + ar2) * HID + k0 + ac2, &sB[s2 * 8]);
    __syncthreads();
    half8 a[4], b[4];
#pragma unroll
    for (int m = 0; m < 4; ++m)
      a[m] = *reinterpret_cast<const half8*>(&sA[(wr + m * 16 + lrow) * 32 + lks * 8]);
#pragma unroll
    for (int n = 0; n < 4; ++n)
      b[n] = *reinterpret_cast<const half8*>(&sB[(wc + n * 16 + lrow) * 32 + lks * 8]);
#pragma unroll
    for (int m = 0; m < 4; ++m)
#pragma unroll
      for (int n = 0; n < 4; ++n)
        acc[m][n] = __builtin_amdgcn_mfma_f32_16x16x32_f16(a[m], b[n], acc[m][n], 0, 0, 0);
  }

  // f16 raw-score write into the packed Sh slots
#pragma unroll
  for (int m = 0; m < 4; ++m)
#pragma unroll
    for (int n = 0; n < 4; ++n)
#pragma unroll
      for (int r = 0; r < 4; ++r)
        Ch[(size_t)(m0 + wr + m * 16 + lks * 4 + r) * (2 * SEQ) + SEQ +
           (n0 + wc + n * 16 + lrow)] = (half_t)acc[m][n][r];

  // per-tile softmax partials
#pragma unroll
  for (int m = 0; m < 4; ++m) {
#pragma unroll
    for (int r = 0; r < 4; ++r) {
      float mx = fmaxf(fmaxf(acc[m][0][r], acc[m][1][r]),
                       fmaxf(acc[m][2][r], acc[m][3][r]));
      mx = fmaxf(mx, __shfl_xor(mx, 1));
      mx = fmaxf(mx, __shfl_xor(mx, 2));
      mx = fmaxf(mx, __shfl_xor(mx, 4));
      mx = fmaxf(mx, __shfl_xor(mx, 8));
      float s = expf(acc[m][0][r] - mx) + expf(acc[m][1][r] - mx) +
                expf(acc[m][2][r] - mx) + expf(acc[m][3][r] - mx);
      s += __shfl_xor(s, 1);
      s += __shfl_xor(s, 2);
      s += __shfl_xor(s, 4);
      s += __shfl_xor(s, 8);
      if (lrow == 0) {
        const int rr = wr + m * 16 + lks * 4 + r;
        lm[wid & 1][rr] = mx;
        ls[wid & 1][rr] = s;
      }
    }
  }
  __syncthreads();
  if (t < 128) {
    const float m0v = lm[0][t], m1v = lm[1][t];
    const float M = fmaxf(m0v, m1v);
    const float L = ls[0][t] * expf(m0v - M) + ls[1][t] * expf(m1v - M);
    part[(size_t)(bz * SEQ + m0 + t) * 32 + blockIdx.x] = make_float2(M, L);
  }
}

// ---------------- merge 32 per-tile partials per row -> (rowmax, 1/rowsum) --------
__global__ void k_lred(const float2* __restrict__ part, float2* __restrict__ stats) {
  const int row = blockIdx.x * 256 + threadIdx.x;  // [0, NB*SEQ)
  const float2* p = part + (size_t)row * 32;
  float M = -3.4028235e38f;
#pragma unroll
  for (int i = 0; i < 32; ++i) M = fmaxf(M, p[i].x);
  float L = 0.f;
#pragma unroll
  for (int i = 0; i < 32; ++i) L += p[i].y * expf(p[i].x - M);
  stats[row] = make_float2(M, 1.0f / L);
}

// ---------------- fused: read f16 Sh -> write f32 attn + opt = attn @ V ----------
// BM=32, BN=512, superchunk=128 cols (32 iters). Sh read 2 superchunks ahead of
// the f32 write front (no overlap, proven per-row). praw ring via global_load_lds
// (wave-uniform LDS base), never vmcnt-drained; barriers lgkm-only.
__launch_bounds__(512, 4)
__global__ void k_pvn(float* __restrict__ P, const half_t* __restrict__ Vf,
                      const float2* __restrict__ stats, float* __restrict__ O) {
  __shared__ half_t sA[4][32 * 64];   // 2 superchunks x 2 chunk-halves, swizzled
  __shared__ half_t praw[2][4096];    // raw f16 Sh ring (2 x 8 KB)
  const int t = threadIdx.x;

  // bijective XCD swizzle: 512 blocks, 64 per XCD
  const int bid = blockIdx.x;
  const int sw = (bid & 7) * 64 + (bid >> 3);
  const int bz = sw >> 7;
  const int m0 = (sw & 127) * 32;

  float* Pb = P + (size_t)bz * SEQ * SEQ;
  const half_t* Vfb = Vf + (size_t)bz * 128 * 32 * 512;
  float* Ob = O + (size_t)bz * SEQ * HID;

  const int lane = t & 63, wid = t >> 6;
  const int lrow = lane & 15, lks = lane >> 4;

  // P map: thread owns 8 cols (granule pc) of row prow in each 128-col superchunk
  const int prow = t >> 4;          // 0..31
  const int pc = t & 15;            // 0..15
  const float2 st = stats[(size_t)bz * SEQ + m0 + prow];
  const float mrow = st.x, invl = st.y;

  float* const PArow = Pb + (size_t)(m0 + prow) * SEQ + pc * 8;
  const half_t* const Shrow =
      (const half_t*)(Pb + (size_t)(m0 + prow) * SEQ) + SEQ + pc * 8;

  const int schunk = pc >> 3;                   // 64-col half within superchunk
  const int sidx = prow * 64 + (((pc & 7) ^ (prow & 7)) << 3);

  // a-frag swizzled read offsets (per chunk-half, proven 0-conflict layout)
  int aoff[2][2];
#pragma unroll
  for (int m = 0; m < 2; ++m)
#pragma unroll
    for (int kk = 0; kk < 2; ++kk) {
      const int row = m * 16 + lrow;
      aoff[m][kk] = row * 64 + (((kk * 4 + lks) ^ (row & 7)) << 3);
    }

  f32x4 acc[2][4] = {};

#define PV_CONSUME(S, PR)                                                    \
  {                                                                          \
    float e[8];                                                              \
    _Pragma("unroll")                                                        \
    for (int j = 0; j < 8; ++j)                                              \
      e[j] = exp2f(((float)(PR)[j] - mrow) * LOG2E) * invl;                  \
    *reinterpret_cast<float4*>(PArow + (S) * 128) =                          \
        make_float4(e[0], e[1], e[2], e[3]);                                 \
    *reinterpret_cast<float4*>(PArow + (S) * 128 + 4) =                      \
        make_float4(e[4], e[5], e[6], e[7]);                                 \
    half8 hv;                                                                \
    _Pragma("unroll")                                                        \
    for (int j = 0; j < 8; ++j) hv[j] = (half_t)e[j];                        \
    *reinterpret_cast<half8*>(&sA[((S) & 1) * 2 + schunk][sidx]) = hv;       \
  }

  // ---- prologue: superchunk 0 direct; issue praw for superchunk 1 ----
  {
    half8 pr = *reinterpret_cast<const half8*>(Shrow);
    PV_CONSUME(0, pr);
    GLOAD_LDS16(Shrow + 128, &praw[1][wid * 512]);
    LGKM_BARRIER();
  }

  for (int sc = 0; sc < 32; ++sc) {
    // V b-frag loads first (16 x 16B, contiguous, L2-resident)
    half8 b[16];
#pragma unroll
    for (int kc = 0; kc < 4; ++kc)
#pragma unroll
      for (int n = 0; n < 4; ++n)
        b[kc * 4 + n] = *reinterpret_cast<const half8*>(
            Vfb + ((size_t)(sc * 4 + kc) * 32 + wid * 4 + n) * 512 + lane * 8);
    // praw stage issued last -> V-reg waits leave it in flight across barriers
    if (sc + 2 < 32)
      GLOAD_LDS16(Shrow + (sc + 2) * 128, &praw[sc & 1][wid * 512]);

    // MFMA: 4 kc-steps (K=128 total per superchunk)
#pragma unroll
    for (int kc = 0; kc < 4; ++kc) {
      const int cb = (sc & 1) * 2 + (kc >> 1);
      half8 a[2];
#pragma unroll
      for (int m = 0; m < 2; ++m)
        a[m] = *reinterpret_cast<const half8*>(&sA[cb][aoff[m][kc & 1]]);
#pragma unroll
      for (int m = 0; m < 2; ++m)
#pragma unroll
        for (int n = 0; n < 4; ++n)
          acc[m][n] = __builtin_amdgcn_mfma_f32_16x16x32_f16(a[m], b[kc * 4 + n],
                                                             acc[m][n], 0, 0, 0);
    }

    // consume superchunk sc+1 (praw issued last iter; older than this iter's V
    // loads, whose compiler wait already forced it complete). vmcnt(1) = insurance.
    if (sc + 1 < 32) {
      asm volatile("s_waitcnt vmcnt(1)" ::: "memory");
      __builtin_amdgcn_sched_barrier(0);
      half8 pr = *reinterpret_cast<const half8*>(&praw[(sc + 1) & 1][t * 8]);
      PV_CONSUME(sc + 1, pr);
      LGKM_BARRIER();
    }
  }

#pragma unroll
  for (int m = 0; m < 2; ++m)
#pragma unroll
    for (int n = 0; n < 4; ++n)
#pragma unroll
      for (int r = 0; r < 4; ++r)
        Ob[(size_t)(m0 + m * 16 + lks * 4 + r) * HID + (wid * 64 + n * 16 + lrow)] =
            acc[m][n][r];
}

extern "C" void kernel_launch(void* const* d_in, const int* in_sizes, int n_in,
                              void* d_out, int out_size, void* d_ws, size_t ws_size,
                              hipStream_t stream) {
  const float* x = (const float*)d_in[0];     // [4,4096,512]
  const float* W = (const float*)d_in[1];     // [512,1536]
  const float* bias = (const float*)d_in[2];  // [1536]
  float* opt = (float*)d_out;                        // [4*4096*512]
  float* attn = opt + (size_t)NB * SEQ * HID;        // [4*4096*4096]

  half_t* xh = (half_t*)d_ws;                        // 16384*512
  half_t* Wt = xh + (size_t)NB * SEQ * HID;          // 1536*512
  half_t* Qh = Wt + (size_t)N3 * HID;                // 16384*512 (scale folded)
  half_t* Kh = Qh + (size_t)NB * SEQ * HID;          // 16384*512
  half_t* Vt = Kh + (size_t)NB * SEQ * HID;          // 4*[512][4096] transposed
  half_t* Vf = Vt + (size_t)NB * HID * SEQ;          // fragment-packed V (16 MB)
  float2* part = (float2*)(Vf + (size_t)NB * HID * SEQ);  // [16384][32]
  float2* stats = part + (size_t)NB * SEQ * 32;           // [16384]

  k_cvt<<<2048, 256, 0, stream>>>(x, xh, NB * SEQ * HID / 4);
  k_tw<<<dim3(N3 / 64, HID / 64), 256, 0, stream>>>(W, Wt);
  k_qkv<<<dim3(N3 / 128, NB * SEQ / 128), 256, 0, stream>>>(xh, Wt, bias, Qh, Kh, Vt);
  k_vrep<<<NB * HID * SEQ / 8 / 256, 256, 0, stream>>>(Vt, Vf);
  k_qk<<<dim3(SEQ / 128, SEQ / 128, NB), 256, 0, stream>>>(Qh, Kh, attn, part);
  k_lred<<<NB * SEQ / 256, 256, 0, stream>>>(part, stats);
  k_pvn<<<512, 512, 0, stream>>>(attn, Vf, stats, opt);
}

// Round 9
// 362.086 us; speedup vs baseline: 1.5525x; 1.0967x over previous
//
#include <hip/hip_runtime.h>

#define SEQ 4096
#define HID 512
#define NB  4
#define N3  1536
#define LOG2E 1.4426950408889634f

typedef _Float16 half_t;
typedef __attribute__((ext_vector_type(8))) _Float16 half8;
typedef __attribute__((ext_vector_type(4))) float f32x4;

#define GLOAD_LDS16(gp, lp) __builtin_amdgcn_global_load_lds((gp), (lp), 16, 0, 0)

#define LGKM_BARRIER()                                                       \
  asm volatile("s_waitcnt lgkmcnt(0)" ::: "memory");                         \
  __builtin_amdgcn_sched_barrier(0);                                         \
  __builtin_amdgcn_s_barrier();

// ---------------- convert x (f32) -> f16 ----------------
__global__ void k_cvt(const float* __restrict__ x, half_t* __restrict__ xh, int n4) {
  int i = blockIdx.x * blockDim.x + threadIdx.x;
  int stride = gridDim.x * blockDim.x;
  for (; i < n4; i += stride) {
    float4 v = reinterpret_cast<const float4*>(x)[i];
    union { half_t h[4]; short4 s; } u;
    u.h[0] = (half_t)v.x; u.h[1] = (half_t)v.y;
    u.h[2] = (half_t)v.z; u.h[3] = (half_t)v.w;
    reinterpret_cast<short4*>(xh)[i] = u.s;
  }
}

// ---------------- W [512][1536] f32 -> Wt [1536][512] f16 ----------------
__global__ void k_tw(const float* __restrict__ W, half_t* __restrict__ Wt) {
  __shared__ half_t tile[64][65];
  const int n0 = blockIdx.x * 64;
  const int k0 = blockIdx.y * 64;
  const int tx = threadIdx.x & 63, ty = threadIdx.x >> 6;
#pragma unroll
  for (int i = 0; i < 64; i += 4)
    tile[ty + i][tx] = (half_t)W[(size_t)(k0 + ty + i) * N3 + n0 + tx];
  __syncthreads();
#pragma unroll
  for (int i = 0; i < 64; i += 4)
    Wt[(size_t)(n0 + ty + i) * HID + k0 + tx] = tile[tx][ty + i];
}

// ---------------- QKV projection GEMM ----------------
__launch_bounds__(256)
__global__ void k_qkv(const half_t* __restrict__ xh, const half_t* __restrict__ Wt,
                      const float* __restrict__ bias,
                      half_t* __restrict__ Qh, half_t* __restrict__ Kh,
                      half_t* __restrict__ Vt) {
  __shared__ half_t sA[128 * 32];
  __shared__ half_t sB[128 * 32];
  const int t = threadIdx.x;
  const int m0 = blockIdx.y * 128;
  const int n0 = blockIdx.x * 128;
  const int lane = t & 63, wid = t >> 6;
  const int wr = (wid >> 1) * 64, wc = (wid & 1) * 64;
  const int lrow = lane & 15, lks = lane >> 4;
  const int s1 = t, s2 = t + 256;
  const int ar1 = s1 >> 2, ac1 = (s1 & 3) * 8;
  const int ar2 = s2 >> 2, ac2 = (s2 & 3) * 8;

  f32x4 acc[4][4] = {};

  for (int k0 = 0; k0 < HID; k0 += 32) {
    __syncthreads();
    GLOAD_LDS16(xh + (size_t)(m0 + ar1) * HID + k0 + ac1, &sA[s1 * 8]);
    GLOAD_LDS16(xh + (size_t)(m0 + ar2) * HID + k0 + ac2, &sA[s2 * 8]);
    GLOAD_LDS16(Wt + (size_t)(n0 + ar1) * HID + k0 + ac1, &sB[s1 * 8]);
    GLOAD_LDS16(Wt + (size_t)(n0 + ar2) * HID + k0 + ac2, &sB[s2 * 8]);
    __syncthreads();
    half8 a[4], b[4];
#pragma unroll
    for (int m = 0; m < 4; ++m)
      a[m] = *reinterpret_cast<const half8*>(&sA[(wr + m * 16 + lrow) * 32 + lks * 8]);
#pragma unroll
    for (int n = 0; n < 4; ++n)
      b[n] = *reinterpret_cast<const half8*>(&sB[(wc + n * 16 + lrow) * 32 + lks * 8]);
#pragma unroll
    for (int m = 0; m < 4; ++m)
#pragma unroll
      for (int n = 0; n < 4; ++n)
        acc[m][n] = __builtin_amdgcn_mfma_f32_16x16x32_f16(a[m], b[n], acc[m][n], 0, 0, 0);
  }

  const float scale = 0.04419417382415922f;  // 1/sqrt(512)
  const int region = n0 >> 9;  // 0=Q, 1=K, 2=V (uniform per block)
#pragma unroll
  for (int m = 0; m < 4; ++m) {
#pragma unroll
    for (int n = 0; n < 4; ++n) {
      const int col = n0 + wc + n * 16 + lrow;
#pragma unroll
      for (int r = 0; r < 4; ++r) {
        const int row = m0 + wr + m * 16 + lks * 4 + r;
        float v = acc[m][n][r] + bias[col];
        if (region == 0) {
          Qh[(size_t)row * HID + col] = (half_t)(v * scale);
        } else if (region == 1) {
          Kh[(size_t)row * HID + (col - 512)] = (half_t)v;
        } else {
          const int bb = row >> 12, ml = row & (SEQ - 1);
          Vt[((size_t)bb * HID + (col - 1024)) * SEQ + ml] = (half_t)v;
        }
      }
    }
  }
}

// ---------------- repack Vt [b][h][s] -> Vf MFMA-fragment tiles ----------------
__global__ void k_vrep(const half_t* __restrict__ Vt, half_t* __restrict__ Vf) {
  const int g = blockIdx.x * 256 + threadIdx.x;   // one half8 per thread
  const int tile = g >> 6, l = g & 63;
  const int bb = tile >> 12;
  const int kc = (tile >> 5) & 127;
  const int hg = tile & 31;
  const int h = hg * 16 + (l & 15);
  const int s = kc * 32 + (l >> 4) * 8;
  half8 v = *reinterpret_cast<const half8*>(&Vt[((size_t)bb * HID + h) * SEQ + s]);
  *reinterpret_cast<half8*>(&Vf[(size_t)tile * 512 + l * 8]) = v;
}

// ---------------- scores = Q @ K^T -> f16 Sh (packed in attn region) + partials --
__launch_bounds__(256)
__global__ void k_qk(const half_t* __restrict__ Qh, const half_t* __restrict__ Kh,
                     float* __restrict__ S, float2* __restrict__ part) {
  __shared__ half_t sA[128 * 32];
  __shared__ half_t sB[128 * 32];
  __shared__ float lm[2][128], ls[2][128];
  const int t = threadIdx.x;
  const int bz = blockIdx.z;
  const half_t* A = Qh + (size_t)bz * SEQ * HID;
  const half_t* B = Kh + (size_t)bz * SEQ * HID;
  half_t* Ch = (half_t*)(S + (size_t)bz * SEQ * SEQ);
  const int m0 = blockIdx.y * 128;
  const int n0 = blockIdx.x * 128;
  const int lane = t & 63, wid = t >> 6;
  const int wr = (wid >> 1) * 64, wc = (wid & 1) * 64;
  const int lrow = lane & 15, lks = lane >> 4;
  const int s1 = t, s2 = t + 256;
  const int ar1 = s1 >> 2, ac1 = (s1 & 3) * 8;
  const int ar2 = s2 >> 2, ac2 = (s2 & 3) * 8;

  f32x4 acc[4][4] = {};

  for (int k0 = 0; k0 < HID; k0 += 32) {
    __syncthreads();
    GLOAD_LDS16(A + (size_t)(m0 + ar1) * HID + k0 + ac1, &sA[s1 * 8]);
    GLOAD_LDS16(A + (size_t)(m0 + ar2) * HID + k0 + ac2, &sA[s2 * 8]);
    GLOAD_LDS16(B + (size_t)(n0 + ar1) * HID + k0 + ac1, &sB[s1 * 8]);
    GLOAD_LDS16(B + (size_t)(n0 + ar2) * HID + k0 + ac2, &sB[s2 * 8]);
    __syncthreads();
    half8 a[4], b[4];
#pragma unroll
    for (int m = 0; m < 4; ++m)
      a[m] = *reinterpret_cast<const half8*>(&sA[(wr + m * 16 + lrow) * 32 + lks * 8]);
#pragma unroll
    for (int n = 0; n < 4; ++n)
      b[n] = *reinterpret_cast<const half8*>(&sB[(wc + n * 16 + lrow) * 32 + lks * 8]);
#pragma unroll
    for (int m = 0; m < 4; ++m)
#pragma unroll
      for (int n = 0; n < 4; ++n)
        acc[m][n] = __builtin_amdgcn_mfma_f32_16x16x32_f16(a[m], b[n], acc[m][n], 0, 0, 0);
  }

  // f16 raw-score write into the packed Sh slots
#pragma unroll
  for (int m = 0; m < 4; ++m)
#pragma unroll
    for (int n = 0; n < 4; ++n)
#pragma unroll
      for (int r = 0; r < 4; ++r)
        Ch[(size_t)(m0 + wr + m * 16 + lks * 4 + r) * (2 * SEQ) + SEQ +
           (n0 + wc + n * 16 + lrow)] = (half_t)acc[m][n][r];

  // per-tile softmax partials
#pragma unroll
  for (int m = 0; m < 4; ++m) {
#pragma unroll
    for (int r = 0; r < 4; ++r) {
      float mx = fmaxf(fmaxf(acc[m][0][r], acc[m][1][r]),
                       fmaxf(acc[m][2][r], acc[m][3][r]));
      mx = fmaxf(mx, __shfl_xor(mx, 1));
      mx = fmaxf(mx, __shfl_xor(mx, 2));
      mx = fmaxf(mx, __shfl_xor(mx, 4));
      mx = fmaxf(mx, __shfl_xor(mx, 8));
      float s = expf(acc[m][0][r] - mx) + expf(acc[m][1][r] - mx) +
                expf(acc[m][2][r] - mx) + expf(acc[m][3][r] - mx);
      s += __shfl_xor(s, 1);
      s += __shfl_xor(s, 2);
      s += __shfl_xor(s, 4);
      s += __shfl_xor(s, 8);
      if (lrow == 0) {
        const int rr = wr + m * 16 + lks * 4 + r;
        lm[wid & 1][rr] = mx;
        ls[wid & 1][rr] = s;
      }
    }
  }
  __syncthreads();
  if (t < 128) {
    const float m0v = lm[0][t], m1v = lm[1][t];
    const float M = fmaxf(m0v, m1v);
    const float L = ls[0][t] * expf(m0v - M) + ls[1][t] * expf(m1v - M);
    part[(size_t)(bz * SEQ + m0 + t) * 32 + blockIdx.x] = make_float2(M, L);
  }
}

// ---------------- merge 32 per-tile partials per row -> (rowmax, 1/rowsum) --------
__global__ void k_lred(const float2* __restrict__ part, float2* __restrict__ stats) {
  const int row = blockIdx.x * 256 + threadIdx.x;  // [0, NB*SEQ)
  const float2* p = part + (size_t)row * 32;
  float M = -3.4028235e38f;
#pragma unroll
  for (int i = 0; i < 32; ++i) M = fmaxf(M, p[i].x);
  float L = 0.f;
#pragma unroll
  for (int i = 0; i < 32; ++i) L += p[i].y * expf(p[i].x - M);
  stats[row] = make_float2(M, 1.0f / L);
}

// ---------------- fused: read f16 Sh -> write f32 attn + opt = attn @ V ----------
// BM=32, BN=512, superchunk=128 cols (32 iters). Raw Sh prefetched to REGISTERS
// (prA/prB, 1-iter lead): pr(sc+1) issued at iter sc-1 is OLDER than V(sc), so the
// MFMA's own V-wait retires it for free; pr(sc+2) issued after V(sc) stays in
// flight. f32 attn stores DEFERRED one iter + NON-TEMPORAL (no L2 thrash, off any
// wait that matters). Barriers lgkm-only. In-place: write front 512(sc+1) B <
// read front 8192+256(sc+2) B for sc<=31; waves barrier-locked per iter.
__launch_bounds__(512, 4)
__global__ void k_pvn(float* __restrict__ P, const half_t* __restrict__ Vf,
                      const float2* __restrict__ stats, float* __restrict__ O) {
  __shared__ half_t sA[4][32 * 64];   // 2 superchunks x 2 halves, XOR-swizzled
  const int t = threadIdx.x;

  // bijective XCD swizzle: 512 blocks, 64 per XCD
  const int bid = blockIdx.x;
  const int sw = (bid & 7) * 64 + (bid >> 3);
  const int bz = sw >> 7;
  const int m0 = (sw & 127) * 32;

  float* Pb = P + (size_t)bz * SEQ * SEQ;
  const half_t* Vfb = Vf + (size_t)bz * 128 * 32 * 512;
  float* Ob = O + (size_t)bz * SEQ * HID;

  const int lane = t & 63, wid = t >> 6;
  const int lrow = lane & 15, lks = lane >> 4;

  // P map: thread owns 8 cols (granule pc) of row prow in each 128-col superchunk
  const int prow = t >> 4;          // 0..31
  const int pc = t & 15;            // 0..15
  const float2 st = stats[(size_t)bz * SEQ + m0 + prow];
  const float mrow2 = st.x * LOG2E, invl = st.y;

  float* const PArow = Pb + (size_t)(m0 + prow) * SEQ + pc * 8;
  const half_t* const Shrow =
      (const half_t*)(Pb + (size_t)(m0 + prow) * SEQ) + SEQ + pc * 8;

  const int schunk = pc >> 3;                   // 64-col half within superchunk
  const int sidx = prow * 64 + (((pc & 7) ^ (prow & 7)) << 3);

  // a-frag swizzled read offsets
  int aoff[2][2];
#pragma unroll
  for (int m = 0; m < 2; ++m)
#pragma unroll
    for (int kk = 0; kk < 2; ++kk) {
      const int row = m * 16 + lrow;
      aoff[m][kk] = row * 64 + (((kk * 4 + lks) ^ (row & 7)) << 3);
    }

  f32x4 acc[2][4] = {};
  f32x4 e0, e1;        // deferred normalized superchunk (8 f32)
  half8 prA, prB;      // raw Sh prefetch registers

#define PV_EXPSTAGE(SB, PR)                                                  \
  {                                                                          \
    _Pragma("unroll")                                                        \
    for (int j = 0; j < 4; ++j) {                                            \
      e0[j] = exp2f((float)(PR)[j] * LOG2E - mrow2) * invl;                  \
      e1[j] = exp2f((float)(PR)[j + 4] * LOG2E - mrow2) * invl;              \
    }                                                                        \
    half8 hv;                                                                \
    _Pragma("unroll")                                                        \
    for (int j = 0; j < 4; ++j) {                                            \
      hv[j] = (half_t)e0[j];                                                 \
      hv[j + 4] = (half_t)e1[j];                                             \
    }                                                                        \
    *reinterpret_cast<half8*>(&sA[(SB) * 2 + schunk][sidx]) = hv;            \
  }

  // iter body: V loads; issue pr(sc+2)->PRL; nt-store e (superchunk sc);
  // MFMA(sc); consume PRC (raw sc+1) -> e + ds_write; barrier.
#define PV_ITER(PRL, PRC, SC)                                                \
  {                                                                          \
    half8 b[16];                                                             \
    _Pragma("unroll")                                                        \
    for (int kc = 0; kc < 4; ++kc)                                           \
      _Pragma("unroll")                                                      \
      for (int n = 0; n < 4; ++n)                                            \
        b[kc * 4 + n] = *reinterpret_cast<const half8*>(                     \
            Vfb + ((size_t)((SC) * 4 + kc) * 32 + wid * 4 + n) * 512 +       \
            lane * 8);                                                       \
    if ((SC) + 2 < 32)                                                       \
      PRL = *reinterpret_cast<const half8*>(Shrow + ((SC) + 2) * 128);       \
    __builtin_nontemporal_store(e0, reinterpret_cast<f32x4*>(PArow + (SC) * 128)); \
    __builtin_nontemporal_store(e1, reinterpret_cast<f32x4*>(PArow + (SC) * 128 + 4)); \
    __builtin_amdgcn_sched_barrier(0);                                       \
    _Pragma("unroll")                                                        \
    for (int kc = 0; kc < 4; ++kc) {                                         \
      const int cb = ((SC) & 1) * 2 + (kc >> 1);                             \
      half8 a[2];                                                            \
      _Pragma("unroll")                                                      \
      for (int m = 0; m < 2; ++m)                                            \
        a[m] = *reinterpret_cast<const half8*>(&sA[cb][aoff[m][kc & 1]]);    \
      _Pragma("unroll")                                                      \
      for (int m = 0; m < 2; ++m)                                            \
        _Pragma("unroll")                                                    \
        for (int n = 0; n < 4; ++n)                                          \
          acc[m][n] = __builtin_amdgcn_mfma_f32_16x16x32_f16(                \
              a[m], b[kc * 4 + n], acc[m][n], 0, 0, 0);                      \
    }                                                                        \
    if ((SC) + 1 < 32) {                                                     \
      PV_EXPSTAGE(((SC) + 1) & 1, PRC);                                      \
    }                                                                        \
    LGKM_BARRIER();                                                          \
  }

  // ---- prologue: consume superchunk 0 direct; issue pr(1) -> prB ----
  {
    half8 pr0 = *reinterpret_cast<const half8*>(Shrow);
    PV_EXPSTAGE(0, pr0);
    prB = *reinterpret_cast<const half8*>(Shrow + 128);
    LGKM_BARRIER();
  }

  for (int sc = 0; sc < 32; sc += 2) {
    PV_ITER(prA, prB, sc);       // loads pr(sc+2) into prA, consumes prB (sc+1)
    PV_ITER(prB, prA, sc + 1);   // loads pr(sc+3) into prB, consumes prA (sc+2)
  }

#pragma unroll
  for (int m = 0; m < 2; ++m)
#pragma unroll
    for (int n = 0; n < 4; ++n)
#pragma unroll
      for (int r = 0; r < 4; ++r)
        Ob[(size_t)(m0 + m * 16 + lks * 4 + r) * HID + (wid * 64 + n * 16 + lrow)] =
            acc[m][n][r];
}

extern "C" void kernel_launch(void* const* d_in, const int* in_sizes, int n_in,
                              void* d_out, int out_size, void* d_ws, size_t ws_size,
                              hipStream_t stream) {
  const float* x = (const float*)d_in[0];     // [4,4096,512]
  const float* W = (const float*)d_in[1];     // [512,1536]
  const float* bias = (const float*)d_in[2];  // [1536]
  float* opt = (float*)d_out;                        // [4*4096*512]
  float* attn = opt + (size_t)NB * SEQ * HID;        // [4*4096*4096]

  half_t* xh = (half_t*)d_ws;                        // 16384*512
  half_t* Wt = xh + (size_t)NB * SEQ * HID;          // 1536*512
  half_t* Qh = Wt + (size_t)N3 * HID;                // 16384*512 (scale folded)
  half_t* Kh = Qh + (size_t)NB * SEQ * HID;          // 16384*512
  half_t* Vt = Kh + (size_t)NB * SEQ * HID;          // 4*[512][4096] transposed
  half_t* Vf = Vt + (size_t)NB * HID * SEQ;          // fragment-packed V (16 MB)
  float2* part = (float2*)(Vf + (size_t)NB * HID * SEQ);  // [16384][32]
  float2* stats = part + (size_t)NB * SEQ * 32;           // [16384]

  k_cvt<<<2048, 256, 0, stream>>>(x, xh, NB * SEQ * HID / 4);
  k_tw<<<dim3(N3 / 64, HID / 64), 256, 0, stream>>>(W, Wt);
  k_qkv<<<dim3(N3 / 128, NB * SEQ / 128), 256, 0, stream>>>(xh, Wt, bias, Qh, Kh, Vt);
  k_vrep<<<NB * HID * SEQ / 8 / 256, 256, 0, stream>>>(Vt, Vf);
  k_qk<<<dim3(SEQ / 128, SEQ / 128, NB), 256, 0, stream>>>(Qh, Kh, attn, part);
  k_lred<<<NB * SEQ / 256, 256, 0, stream>>>(part, stats);
  k_pvn<<<512, 512, 0, stream>>>(attn, Vf, stats, opt);
}